// Round 5
// baseline (1121.186 us; speedup 1.0000x reference)
//
#include <hip/hip_runtime.h>

// Problem constants
#define NROWS   16384      // 16*32*32 flattened (b,h,w) rows
#define KCODES  8192
#define CDIM    256
#define HWS     1024       // 32*32
#define BSTRIDE 262144     // 256*1024 floats per batch in z / out

// Workspace layout (float-unit offsets) -- unchanged from rounds 1-4
#define WS_AN   0                         // ||x||^2 per row       [16384]
#define WS_CE   16384                     // ||e||^2 per code      [8192]
#define WS_CD   24576                     // cand dist [n*4+slice] [65536]
#define WS_CI   90112                     // cand idx  (int)       [65536]
#define WS_IDX  155648                    // final idx (int)       [16384]
#define WS_LOSS 172032                    // loss accumulator      [1]

// -------- row norms, replicating numpy pairwise_sum order exactly --------
__global__ void rownorm_z_k(const float* __restrict__ z, float* __restrict__ An) {
#pragma clang fp contract(off)
  int n = blockIdx.x * 256 + threadIdx.x;                    // 16384 threads
  const float* base = z + ((size_t)(n >> 10)) * BSTRIDE + (n & 1023);
  float hs[2];
  for (int h = 0; h < 2; ++h) {
    float r[8];
#pragma unroll
    for (int j = 0; j < 8; ++j) { float v = base[(size_t)(h * 128 + j) * HWS]; r[j] = v * v; }
    for (int m = 1; m < 16; ++m) {
#pragma unroll
      for (int j = 0; j < 8; ++j) { float v = base[(size_t)(h * 128 + m * 8 + j) * HWS]; r[j] += v * v; }
    }
    hs[h] = ((r[0] + r[1]) + (r[2] + r[3])) + ((r[4] + r[5]) + (r[6] + r[7]));
  }
  An[n] = hs[0] + hs[1];
}

__global__ void rownorm_e_k(const float* __restrict__ emb, float* __restrict__ Ce) {
#pragma clang fp contract(off)
  int n = blockIdx.x * 256 + threadIdx.x;                    // 8192 threads
  const float* base = emb + (size_t)n * CDIM;
  float hs[2];
  for (int h = 0; h < 2; ++h) {
    float r[8];
#pragma unroll
    for (int j = 0; j < 8; ++j) { float v = base[h * 128 + j]; r[j] = v * v; }
    for (int m = 1; m < 16; ++m) {
#pragma unroll
      for (int j = 0; j < 8; ++j) { float v = base[h * 128 + m * 8 + j]; r[j] += v * v; }
    }
    hs[h] = ((r[0] + r[1]) + (r[2] + r[3])) + ((r[4] + r[5]) + (r[6] + r[7]));
  }
  Ce[n] = hs[0] + hs[1];
}

// -------- fused distance + argmin --------
// 1024 blocks = 256 row-tiles (64 rows) x 4 code-slices (2048 codes each).
// 256 threads = 16 tx (codes, 4 each) x 16 ty (rows, 4 each). Micro-tile 4x4.
//
// Wave geometry is the round-5 change: with 16 tx per wave (not 32), a B
// ds_read_b128 touches 16 unique 16B addresses = 256 B = 2 bank phases
// (rounds 3-4 had 32 unique = 512 B = 4+ phases + ~1.9 conflict cyc/instr,
// SQ_LDS_BANK_CONFLICT 6.3e7; LDS-pipe time ~ VALU time and they serialized).
// Register budget (rounds 1-3 lesson): allocator targets 64 VGPR; live set
// here ~55 incl. 8 prefetch regs -> no spill (WRITE_SIZE is the tripwire).
// Long prefetch kept: loads for (kc,cc+1) issued before the 512-cyc FMA phase.
// As stride 20: (r*20+g*4)*4B is 16B-aligned -> ds_read_b128.
__global__ void __launch_bounds__(256)
vq_argmin_k(const float* __restrict__ z, const float* __restrict__ emb,
            const float* __restrict__ An, const float* __restrict__ Ce,
            float* __restrict__ cand_d, int* __restrict__ cand_i) {
  __shared__ float As[64 * 20];    // [row][c_local]
  __shared__ float Bs[16 * 68];    // [c_local][code 0..63], pad 68
  __shared__ float redd[64 * 16];
  __shared__ int   redi[64 * 16];

  const int t  = threadIdx.x;
  const int tx = t & 15;           // code group (4 codes each)
  const int ty = t >> 4;           // row group (4 rows each)
  const int tile  = blockIdx.x >> 2;
  const int slice = blockIdx.x & 3;
  const int rbase = tile * 64;     // 64-row tiles never cross the 1024-hw batch edge
  const int k0    = slice * 2048;

  const float* zb = z + ((size_t)(rbase >> 10)) * BSTRIDE + (rbase & 1023);

  float A_reg[4];
#pragma unroll
  for (int ri = 0; ri < 4; ++ri) A_reg[ri] = An[rbase + ty * 4 + ri];

  float best[4];
  int   bidx[4];
#pragma unroll
  for (int ri = 0; ri < 4; ++ri) { best[ri] = 3.4028235e38f; bidx[ri] = 0; }

  float acc[4][4];
#pragma unroll
  for (int ri = 0; ri < 4; ++ri)
#pragma unroll
    for (int ki = 0; ki < 4; ++ki) acc[ri][ki] = 0.f;

  // staging thread mappings
  const int a_c   = t >> 4;         // c_local 0..15
  const int a_hw  = (t & 15) * 4;   // 4 consecutive rows via float4
  const int b_cd  = t >> 2;         // code 0..63
  const int b_cp  = (t & 3) * 4;    // c_local offset 0/4/8/12

  const float* pAb = zb + (size_t)a_c * HWS + a_hw;                 // A, chunk cc at +cc*16*HWS
  const float* pBb = emb + (size_t)(k0 + b_cd) * CDIM + b_cp;       // B, kc at +kc*64*CDIM, cc at +cc*16

  // prefetch chunk (kc=0, cc=0)
  float4 pa = *(const float4*)(pAb);
  float4 pb = *(const float4*)(pBb);

  const float* pB = pBb;            // current kc base
  for (int kc = 0; kc < 32; ++kc) {
#pragma unroll 4
    for (int cc = 0; cc < 16; ++cc) {
      __syncthreads();                    // prior compute done with As/Bs
      As[(a_hw + 0) * 20 + a_c] = pa.x;   // transpose hw-major load -> [row][c]
      As[(a_hw + 1) * 20 + a_c] = pa.y;
      As[(a_hw + 2) * 20 + a_c] = pa.z;
      As[(a_hw + 3) * 20 + a_c] = pa.w;
      Bs[(b_cp + 0) * 68 + b_cd] = pb.x;
      Bs[(b_cp + 1) * 68 + b_cd] = pb.y;
      Bs[(b_cp + 2) * 68 + b_cd] = pb.z;
      Bs[(b_cp + 3) * 68 + b_cd] = pb.w;
      __syncthreads();                    // staged data visible

      // long prefetch for (kc, cc+1) -- wraps (kc+1, 0) at cc==15, and to
      // (0,0) at the very end (harmless in-bounds load, never stored)
      {
        const int ncc = (cc + 1) & 15;
        pa = *(const float4*)(pAb + (size_t)ncc * (16 * HWS));
        const float* nB = (cc == 15) ? ((kc == 31) ? pBb : pB + 64 * CDIM) : pB;
        pb = *(const float4*)(nB + ncc * 16);
      }

      // 4x4 micro-tile over 16 c: 256 fp32 FMAs / thread
      // (dot-product chain order identical to rounds 1-4: bit-identical)
#pragma unroll
      for (int g = 0; g < 4; ++g) {
        const float4 b0 = *(const float4*)&Bs[(g * 4 + 0) * 68 + tx * 4];
        const float4 b1 = *(const float4*)&Bs[(g * 4 + 1) * 68 + tx * 4];
        const float4 b2 = *(const float4*)&Bs[(g * 4 + 2) * 68 + tx * 4];
        const float4 b3 = *(const float4*)&Bs[(g * 4 + 3) * 68 + tx * 4];
#pragma unroll
        for (int ri = 0; ri < 4; ++ri) {
          const float4 a = *(const float4*)&As[(ty * 4 + ri) * 20 + g * 4];
          acc[ri][0] = fmaf(a.x, b0.x, fmaf(a.y, b1.x, fmaf(a.z, b2.x, fmaf(a.w, b3.x, acc[ri][0]))));
          acc[ri][1] = fmaf(a.x, b0.y, fmaf(a.y, b1.y, fmaf(a.z, b2.y, fmaf(a.w, b3.y, acc[ri][1]))));
          acc[ri][2] = fmaf(a.x, b0.z, fmaf(a.y, b1.z, fmaf(a.z, b2.z, fmaf(a.w, b3.z, acc[ri][2]))));
          acc[ri][3] = fmaf(a.x, b0.w, fmaf(a.y, b1.w, fmaf(a.z, b2.w, fmaf(a.w, b3.w, acc[ri][3]))));
        }
      }
    }

    // fold per kc: dist = (A - 2*dot) + C with np's elementwise fp32 rounding.
    // k ascending + strict < keeps lowest-index min, matching np.argmin ties.
    {
      const int kk = k0 + kc * 64 + tx * 4;
      const float4 ce = *(const float4*)&Ce[kk];
#pragma unroll
      for (int ri = 0; ri < 4; ++ri) {
        const float Ar = A_reg[ri];
        const float d0 = (Ar - 2.0f * acc[ri][0]) + ce.x;
        const float d1 = (Ar - 2.0f * acc[ri][1]) + ce.y;
        const float d2 = (Ar - 2.0f * acc[ri][2]) + ce.z;
        const float d3 = (Ar - 2.0f * acc[ri][3]) + ce.w;
        if (d0 < best[ri]) { best[ri] = d0; bidx[ri] = kk; }
        if (d1 < best[ri]) { best[ri] = d1; bidx[ri] = kk + 1; }
        if (d2 < best[ri]) { best[ri] = d2; bidx[ri] = kk + 2; }
        if (d3 < best[ri]) { best[ri] = d3; bidx[ri] = kk + 3; }
        acc[ri][0] = 0.f; acc[ri][1] = 0.f; acc[ri][2] = 0.f; acc[ri][3] = 0.f;
      }
    }
    pB += 64 * CDIM;
  }

  // cross-thread argmin per row (tie -> lower absolute index)
#pragma unroll
  for (int ri = 0; ri < 4; ++ri) {
    redd[(ty * 4 + ri) * 16 + tx] = best[ri];
    redi[(ty * 4 + ri) * 16 + tx] = bidx[ri];
  }
  __syncthreads();
  if (t < 64) {
    float bd = redd[t * 16];
    int   bi = redi[t * 16];
    for (int j = 1; j < 16; ++j) {
      const float d  = redd[t * 16 + j];
      const int   i2 = redi[t * 16 + j];
      if (d < bd || (d == bd && i2 < bi)) { bd = d; bi = i2; }
    }
    const int n = rbase + t;
    cand_d[n * 4 + slice] = bd;
    cand_i[n * 4 + slice] = bi;
  }
}

// -------- merge the 4 code-slices (tie -> lower index) --------
__global__ void vq_merge_k(const float* __restrict__ cand_d, const int* __restrict__ cand_i,
                           int* __restrict__ idx_final, float* __restrict__ idxf_out) {
  const int n = blockIdx.x * 256 + threadIdx.x;   // 16384
  float bd = cand_d[n * 4];
  int   bi = cand_i[n * 4];
#pragma unroll
  for (int s = 1; s < 4; ++s) {
    const float d  = cand_d[n * 4 + s];
    const int   i2 = cand_i[n * 4 + s];
    if (d < bd || (d == bd && i2 < bi)) { bd = d; bi = i2; }
  }
  idx_final[n] = bi;
  idxf_out[n] = (float)bi;
}

// -------- gather quantized, write straight-through output, accumulate loss ----
// quantized_st = z + (q - z) in fp32 (matches np rounding; != q exactly).
__launch_bounds__(256)
__global__ void vq_gather_loss_k(const float* __restrict__ z, const float* __restrict__ emb,
                                 const int* __restrict__ idx_final,
                                 float* __restrict__ qout, float* __restrict__ loss_acc) {
  __shared__ float Qs[32 * 260];
  __shared__ int   kidx[32];
  __shared__ float warp_s[4];
  const int t = threadIdx.x;
  const int rbase = blockIdx.x * 32;
  if (t < 32) kidx[t] = idx_final[rbase + t];
  __syncthreads();
  {
    const int r = t >> 3, cp = t & 7;
    const float4* er = (const float4*)(emb + (size_t)kidx[r] * CDIM);
#pragma unroll
    for (int j = 0; j < 8; ++j) {
      const int c4 = cp + j * 8;
      const float4 v = er[c4];
      *(float4*)&Qs[r * 260 + c4 * 4] = v;
    }
  }
  __syncthreads();
  const int b = rbase >> 10, hw0 = rbase & 1023;
  const float* zb = z + (size_t)b * BSTRIDE + hw0;
  float* qb = qout + (size_t)b * BSTRIDE + hw0;
  float s = 0.f;
  const int hwl = t & 31, cg = t >> 5;
  for (int i = 0; i < 32; ++i) {
    const int c = cg * 32 + i;
    const float q  = Qs[hwl * 260 + c];
    const size_t off = (size_t)c * HWS + hwl;
    const float zv = zb[off];
    const float d  = q - zv;
    qb[off] = zv + d;          // straight-through value, np rounding
    s += d * d;
  }
  for (int off = 32; off; off >>= 1) s += __shfl_down(s, off, 64);
  if ((t & 63) == 0) warp_s[t >> 6] = s;
  __syncthreads();
  if (t == 0) atomicAdd(loss_acc, warp_s[0] + warp_s[1] + warp_s[2] + warp_s[3]);
}

__global__ void vq_finalize_k(const float* __restrict__ loss_acc, float* __restrict__ out_loss) {
  const float m = loss_acc[0] * (1.0f / 4194304.0f);
  out_loss[0] = m;          // codebook_loss
  out_loss[1] = 0.25f * m;  // commitment_loss (BETA * same mean)
}

extern "C" void kernel_launch(void* const* d_in, const int* in_sizes, int n_in,
                              void* d_out, int out_size, void* d_ws, size_t ws_size,
                              hipStream_t stream) {
  (void)in_sizes; (void)n_in; (void)out_size; (void)ws_size;
  const float* z   = (const float*)d_in[0];
  const float* emb = (const float*)d_in[1];
  float* out      = (float*)d_out;
  float* q_out    = out;                 // [16,256,32,32]
  float* loss_out = out + 4194304;       // 2 scalars
  float* idxf_out = out + 4194306;       // [16,32,32] as float

  float* ws       = (float*)d_ws;
  float* An       = ws + WS_AN;
  float* Ce       = ws + WS_CE;
  float* cand_d   = ws + WS_CD;
  int*   cand_i   = (int*)(ws + WS_CI);
  int*   idx_fin  = (int*)(ws + WS_IDX);
  float* loss_acc = ws + WS_LOSS;

  hipMemsetAsync(loss_acc, 0, sizeof(float), stream);
  rownorm_z_k<<<64, 256, 0, stream>>>(z, An);
  rownorm_e_k<<<32, 256, 0, stream>>>(emb, Ce);
  vq_argmin_k<<<1024, 256, 0, stream>>>(z, emb, An, Ce, cand_d, cand_i);
  vq_merge_k<<<64, 256, 0, stream>>>(cand_d, cand_i, idx_fin, idxf_out);
  vq_gather_loss_k<<<512, 256, 0, stream>>>(z, emb, idx_fin, q_out, loss_acc);
  vq_finalize_k<<<1, 1, 0, stream>>>(loss_acc, loss_out);
}

// Round 6
// 1103.681 us; speedup vs baseline: 1.0159x; 1.0159x over previous
//
#include <hip/hip_runtime.h>

// Problem constants
#define NROWS   16384      // 16*32*32 flattened (b,h,w) rows
#define KCODES  8192
#define CDIM    256
#define HWS     1024       // 32*32
#define BSTRIDE 262144     // 256*1024 floats per batch in z / out

// Workspace layout (float-unit offsets) -- unchanged
#define WS_AN   0                         // ||x||^2 per row       [16384]
#define WS_CE   16384                     // ||e||^2 per code      [8192]
#define WS_CD   24576                     // cand dist [n*4+slice] [65536]
#define WS_CI   90112                     // cand idx  (int)       [65536]
#define WS_IDX  155648                    // final idx (int)       [16384]
#define WS_LOSS 172032                    // loss accumulator      [1]

// -------- row norms, replicating numpy pairwise_sum order exactly --------
__global__ void rownorm_z_k(const float* __restrict__ z, float* __restrict__ An) {
#pragma clang fp contract(off)
  int n = blockIdx.x * 256 + threadIdx.x;                    // 16384 threads
  const float* base = z + ((size_t)(n >> 10)) * BSTRIDE + (n & 1023);
  float hs[2];
  for (int h = 0; h < 2; ++h) {
    float r[8];
#pragma unroll
    for (int j = 0; j < 8; ++j) { float v = base[(size_t)(h * 128 + j) * HWS]; r[j] = v * v; }
    for (int m = 1; m < 16; ++m) {
#pragma unroll
      for (int j = 0; j < 8; ++j) { float v = base[(size_t)(h * 128 + m * 8 + j) * HWS]; r[j] += v * v; }
    }
    hs[h] = ((r[0] + r[1]) + (r[2] + r[3])) + ((r[4] + r[5]) + (r[6] + r[7]));
  }
  An[n] = hs[0] + hs[1];
}

__global__ void rownorm_e_k(const float* __restrict__ emb, float* __restrict__ Ce) {
#pragma clang fp contract(off)
  int n = blockIdx.x * 256 + threadIdx.x;                    // 8192 threads
  const float* base = emb + (size_t)n * CDIM;
  float hs[2];
  for (int h = 0; h < 2; ++h) {
    float r[8];
#pragma unroll
    for (int j = 0; j < 8; ++j) { float v = base[h * 128 + j]; r[j] = v * v; }
    for (int m = 1; m < 16; ++m) {
#pragma unroll
      for (int j = 0; j < 8; ++j) { float v = base[h * 128 + m * 8 + j]; r[j] += v * v; }
    }
    hs[h] = ((r[0] + r[1]) + (r[2] + r[3])) + ((r[4] + r[5]) + (r[6] + r[7]));
  }
  Ce[n] = hs[0] + hs[1];
}

// -------- fused distance + argmin --------
// 512 blocks = 128 row-tiles (128 rows) x 4 code-slices (2048 codes each).
// 256 threads = 16 tx (codes, 8 each) x 16 ty (rows, 8 each). Micro-tile 8x8.
//
// Design driver (round-5 lesson): the kernel was LDS-READ-ISSUE bound, not
// bank-conflict bound. A wave64 ds_read_b128 costs ~8-12 LDS-unit cycles
// regardless of broadcast (m134); the 4x4 tile did 32 reads per 256 FMA
// instrs -> LDS:VALU = 2.5:1 -> the measured ~1.05 ms plateau. 8x8 tile:
// 64 reads per 1024 FMA instrs -> 1.25:1 -> ~550 us predicted.
// Both tiles stored row-major [row][16 k] with XOR swizzle on the k-group
// ((row>>3)&3): keeps all b128 reads/writes 16B-aligned (pad would break
// row-stride-8 bank spread; swizzle de-aliases it).
// Registers: acc 64 + b-frag 32 + transient a 4 + best/bidx 16 + addr ~12
// ~= 128. Short prefetch (regs die at LDS stores; round 3-vs-4 showed short
// == long) and An reloaded at fold (-8 regs). WRITE_SIZE is the spill
// tripwire (rounds 1-2: allocator squeeze -> GBs of scratch traffic).
__global__ void __launch_bounds__(256)
vq_argmin_k(const float* __restrict__ z, const float* __restrict__ emb,
            const float* __restrict__ An, const float* __restrict__ Ce,
            float* __restrict__ cand_d, int* __restrict__ cand_i) {
  __shared__ float As[128 * 16];   // [row][k-chunk 16], XOR-swizzled k-groups
  __shared__ float Bs[128 * 16];   // [code][k-chunk 16], XOR-swizzled k-groups
  __shared__ float redd[128 * 16];
  __shared__ int   redi[128 * 16];

  const int t  = threadIdx.x;
  const int tx = t & 15;           // code group (8 codes each)
  const int ty = t >> 4;           // row group (8 rows each)
  const int tile  = blockIdx.x >> 2;
  const int slice = blockIdx.x & 3;
  const int rbase = tile * 128;    // 128-row tiles never cross the 1024-hw batch edge
  const int k0    = slice * 2048;

  const float* zb = z + ((size_t)(rbase >> 10)) * BSTRIDE + (rbase & 1023);

  float best[8];
  int   bidx[8];
#pragma unroll
  for (int ri = 0; ri < 8; ++ri) { best[ri] = 3.4028235e38f; bidx[ri] = 0; }

  float acc[8][8];
#pragma unroll
  for (int ri = 0; ri < 8; ++ri)
#pragma unroll
    for (int ci = 0; ci < 8; ++ci) acc[ri][ci] = 0.f;

  // staging thread mappings
  const int a_c    = t >> 4;        // c_local 0..15 (one c, 8 hw)
  const int a_hw   = (t & 15) * 8;  // 8 consecutive rows
  const int b_code = t >> 1;        // code 0..127
  const int b_cp   = (t & 1) * 8;   // c_local 0 or 8 (two float4)

  // swizzle constants
  const int a_sw_col = (a_c & 3);           // in-group float offset for A store
  const int a_grp    = (a_c >> 2);          // k-group of staged c
  const int b_sw     = (b_code >> 3) & 3;   // B store row swizzle
  const int b_g0     = (b_cp >> 2);         // 0 or 2
  const int rd_a_sw  = ty & 3;              // A read swizzle ((row>>3)&3, ri<8)
  const int rd_b_sw  = tx & 3;              // B read swizzle

  for (int kc = 0; kc < 16; ++kc) {
    const int kbase = k0 + kc * 128;
#pragma unroll 1
    for (int cc = 0; cc < 16; ++cc) {
      // short prefetch: issue just before barrier; regs die at the stores
      const float* zsrc = zb + (size_t)(cc * 16 + a_c) * HWS + a_hw;
      const float4 pa0 = *(const float4*)(zsrc);
      const float4 pa1 = *(const float4*)(zsrc + 4);
      const float* bsrc = emb + (size_t)(kbase + b_code) * CDIM + cc * 16 + b_cp;
      const float4 pb0 = *(const float4*)(bsrc);
      const float4 pb1 = *(const float4*)(bsrc + 4);

      __syncthreads();                      // prior compute done with As/Bs
      {
        // A transpose-store: 8 scalar stores, column swizzled per row
        const float va[8] = {pa0.x, pa0.y, pa0.z, pa0.w, pa1.x, pa1.y, pa1.z, pa1.w};
#pragma unroll
        for (int j = 0; j < 8; ++j) {
          const int row = a_hw + j;
          const int col = (((a_grp) ^ ((row >> 3) & 3)) << 2) | a_sw_col;
          As[(row << 4) + col] = va[j];
        }
        // B store: two aligned float4 at swizzled k-group slots
        *(float4*)&Bs[(b_code << 4) + (((b_g0 + 0) ^ b_sw) << 2)] = pb0;
        *(float4*)&Bs[(b_code << 4) + (((b_g0 + 1) ^ b_sw) << 2)] = pb1;
      }
      __syncthreads();                      // staged data visible

      // 8x8 micro-tile over 16 k: 1024 FMA instrs, 64 b128 reads
#pragma unroll
      for (int g = 0; g < 4; ++g) {
        float4 bf[8];
#pragma unroll
        for (int ci = 0; ci < 8; ++ci)
          bf[ci] = *(const float4*)&Bs[((tx * 8 + ci) << 4) + ((g ^ rd_b_sw) << 2)];
#pragma unroll
        for (int ri = 0; ri < 8; ++ri) {
          const float4 a = *(const float4*)&As[((ty * 8 + ri) << 4) + ((g ^ rd_a_sw) << 2)];
#pragma unroll
          for (int ci = 0; ci < 8; ++ci) {
            // chain order identical to rounds 1-5 (k3 innermost-first): bit-exact
            acc[ri][ci] = fmaf(a.x, bf[ci].x, fmaf(a.y, bf[ci].y,
                          fmaf(a.z, bf[ci].z, fmaf(a.w, bf[ci].w, acc[ri][ci]))));
          }
        }
      }
    }

    // fold per kc: dist = (A - 2*dot) + C with np's elementwise fp32 rounding.
    // codes ascending + strict < keeps lowest-index min (np.argmin ties).
    {
      const int kkb = kbase + tx * 8;
      const float4 ce0 = *(const float4*)&Ce[kkb];
      const float4 ce1 = *(const float4*)&Ce[kkb + 4];
      const float cearr[8] = {ce0.x, ce0.y, ce0.z, ce0.w, ce1.x, ce1.y, ce1.z, ce1.w};
#pragma unroll
      for (int ri = 0; ri < 8; ++ri) {
        const float Ar = An[rbase + ty * 8 + ri];   // reload (saves 8 live regs)
#pragma unroll
        for (int ci = 0; ci < 8; ++ci) {
          const float d = (Ar - 2.0f * acc[ri][ci]) + cearr[ci];
          if (d < best[ri]) { best[ri] = d; bidx[ri] = kkb + ci; }
          acc[ri][ci] = 0.f;
        }
      }
    }
  }

  // cross-thread argmin per row (tie -> lower absolute index)
#pragma unroll
  for (int ri = 0; ri < 8; ++ri) {
    redd[(ty * 8 + ri) * 16 + tx] = best[ri];
    redi[(ty * 8 + ri) * 16 + tx] = bidx[ri];
  }
  __syncthreads();
  if (t < 128) {
    float bd = redd[t * 16];
    int   bi = redi[t * 16];
    for (int j = 1; j < 16; ++j) {
      const float d  = redd[t * 16 + j];
      const int   i2 = redi[t * 16 + j];
      if (d < bd || (d == bd && i2 < bi)) { bd = d; bi = i2; }
    }
    const int n = rbase + t;
    cand_d[n * 4 + slice] = bd;
    cand_i[n * 4 + slice] = bi;
  }
}

// -------- merge the 4 code-slices (tie -> lower index) --------
__global__ void vq_merge_k(const float* __restrict__ cand_d, const int* __restrict__ cand_i,
                           int* __restrict__ idx_final, float* __restrict__ idxf_out) {
  const int n = blockIdx.x * 256 + threadIdx.x;   // 16384
  float bd = cand_d[n * 4];
  int   bi = cand_i[n * 4];
#pragma unroll
  for (int s = 1; s < 4; ++s) {
    const float d  = cand_d[n * 4 + s];
    const int   i2 = cand_i[n * 4 + s];
    if (d < bd || (d == bd && i2 < bi)) { bd = d; bi = i2; }
  }
  idx_final[n] = bi;
  idxf_out[n] = (float)bi;
}

// -------- gather quantized, write straight-through output, accumulate loss ----
// quantized_st = z + (q - z) in fp32 (matches np rounding; != q exactly).
__launch_bounds__(256)
__global__ void vq_gather_loss_k(const float* __restrict__ z, const float* __restrict__ emb,
                                 const int* __restrict__ idx_final,
                                 float* __restrict__ qout, float* __restrict__ loss_acc) {
  __shared__ float Qs[32 * 260];
  __shared__ int   kidx[32];
  __shared__ float warp_s[4];
  const int t = threadIdx.x;
  const int rbase = blockIdx.x * 32;
  if (t < 32) kidx[t] = idx_final[rbase + t];
  __syncthreads();
  {
    const int r = t >> 3, cp = t & 7;
    const float4* er = (const float4*)(emb + (size_t)kidx[r] * CDIM);
#pragma unroll
    for (int j = 0; j < 8; ++j) {
      const int c4 = cp + j * 8;
      const float4 v = er[c4];
      *(float4*)&Qs[r * 260 + c4 * 4] = v;
    }
  }
  __syncthreads();
  const int b = rbase >> 10, hw0 = rbase & 1023;
  const float* zb = z + (size_t)b * BSTRIDE + hw0;
  float* qb = qout + (size_t)b * BSTRIDE + hw0;
  float s = 0.f;
  const int hwl = t & 31, cg = t >> 5;
  for (int i = 0; i < 32; ++i) {
    const int c = cg * 32 + i;
    const float q  = Qs[hwl * 260 + c];
    const size_t off = (size_t)c * HWS + hwl;
    const float zv = zb[off];
    const float d  = q - zv;
    qb[off] = zv + d;          // straight-through value, np rounding
    s += d * d;
  }
  for (int off = 32; off; off >>= 1) s += __shfl_down(s, off, 64);
  if ((t & 63) == 0) warp_s[t >> 6] = s;
  __syncthreads();
  if (t == 0) atomicAdd(loss_acc, warp_s[0] + warp_s[1] + warp_s[2] + warp_s[3]);
}

__global__ void vq_finalize_k(const float* __restrict__ loss_acc, float* __restrict__ out_loss) {
  const float m = loss_acc[0] * (1.0f / 4194304.0f);
  out_loss[0] = m;          // codebook_loss
  out_loss[1] = 0.25f * m;  // commitment_loss (BETA * same mean)
}

extern "C" void kernel_launch(void* const* d_in, const int* in_sizes, int n_in,
                              void* d_out, int out_size, void* d_ws, size_t ws_size,
                              hipStream_t stream) {
  (void)in_sizes; (void)n_in; (void)out_size; (void)ws_size;
  const float* z   = (const float*)d_in[0];
  const float* emb = (const float*)d_in[1];
  float* out      = (float*)d_out;
  float* q_out    = out;                 // [16,256,32,32]
  float* loss_out = out + 4194304;       // 2 scalars
  float* idxf_out = out + 4194306;       // [16,32,32] as float

  float* ws       = (float*)d_ws;
  float* An       = ws + WS_AN;
  float* Ce       = ws + WS_CE;
  float* cand_d   = ws + WS_CD;
  int*   cand_i   = (int*)(ws + WS_CI);
  int*   idx_fin  = (int*)(ws + WS_IDX);
  float* loss_acc = ws + WS_LOSS;

  hipMemsetAsync(loss_acc, 0, sizeof(float), stream);
  rownorm_z_k<<<64, 256, 0, stream>>>(z, An);
  rownorm_e_k<<<32, 256, 0, stream>>>(emb, Ce);
  vq_argmin_k<<<512, 256, 0, stream>>>(z, emb, An, Ce, cand_d, cand_i);
  vq_merge_k<<<64, 256, 0, stream>>>(cand_d, cand_i, idx_fin, idxf_out);
  vq_gather_loss_k<<<512, 256, 0, stream>>>(z, emb, idx_fin, q_out, loss_acc);
  vq_finalize_k<<<1, 1, 0, stream>>>(loss_acc, loss_out);
}

// Round 7
// 1001.388 us; speedup vs baseline: 1.1196x; 1.1022x over previous
//
#include <hip/hip_runtime.h>

// Problem constants
#define NROWS   16384      // 16*32*32 flattened (b,h,w) rows
#define KCODES  8192
#define CDIM    256
#define HWS     1024       // 32*32
#define BSTRIDE 262144     // 256*1024 floats per batch in z / out

// Workspace layout (float-unit offsets) -- 8 slices now
#define WS_AN   0                         // ||x||^2 per row       [16384]
#define WS_CE   16384                     // ||e||^2 per code      [8192]
#define WS_CD   24576                     // cand dist [n*8+slice] [131072]
#define WS_CI   155648                    // cand idx  (int)       [131072]
#define WS_IDX  286720                    // final idx (int)       [16384]
#define WS_LOSS 303104                    // loss accumulator      [1]

// -------- row norms, replicating numpy pairwise_sum order exactly --------
__global__ void rownorm_z_k(const float* __restrict__ z, float* __restrict__ An) {
#pragma clang fp contract(off)
  int n = blockIdx.x * 256 + threadIdx.x;                    // 16384 threads
  const float* base = z + ((size_t)(n >> 10)) * BSTRIDE + (n & 1023);
  float hs[2];
  for (int h = 0; h < 2; ++h) {
    float r[8];
#pragma unroll
    for (int j = 0; j < 8; ++j) { float v = base[(size_t)(h * 128 + j) * HWS]; r[j] = v * v; }
    for (int m = 1; m < 16; ++m) {
#pragma unroll
      for (int j = 0; j < 8; ++j) { float v = base[(size_t)(h * 128 + m * 8 + j) * HWS]; r[j] += v * v; }
    }
    hs[h] = ((r[0] + r[1]) + (r[2] + r[3])) + ((r[4] + r[5]) + (r[6] + r[7]));
  }
  An[n] = hs[0] + hs[1];
}

__global__ void rownorm_e_k(const float* __restrict__ emb, float* __restrict__ Ce) {
#pragma clang fp contract(off)
  int n = blockIdx.x * 256 + threadIdx.x;                    // 8192 threads
  const float* base = emb + (size_t)n * CDIM;
  float hs[2];
  for (int h = 0; h < 2; ++h) {
    float r[8];
#pragma unroll
    for (int j = 0; j < 8; ++j) { float v = base[h * 128 + j]; r[j] = v * v; }
    for (int m = 1; m < 16; ++m) {
#pragma unroll
      for (int j = 0; j < 8; ++j) { float v = base[h * 128 + m * 8 + j]; r[j] += v * v; }
    }
    hs[h] = ((r[0] + r[1]) + (r[2] + r[3])) + ((r[4] + r[5]) + (r[6] + r[7]));
  }
  Ce[n] = hs[0] + hs[1];
}

// -------- fused distance + argmin --------
// 1024 blocks = 128 row-tiles (128 rows) x 8 code-slices (1024 codes each)
// -> 4 blocks/CU (round 6 had 512 blocks = 2/CU, Occupancy 20%: grid-bound).
// 256 threads = 16 tx x 16 ty. Micro-tile 8 rows x 8 codes.
//
// Bank model (round-6 lesson, wave64 b128): cost = ceil(distinct-addr
// bank-quad load / 1). B reads: thread's codes are tx + ci*16 (stride 16,
// ascending -> tie-break safe) with swizzle s(code)=(code>>1)&3, so quad =
// 4*(tx&1) + (g ^ ((tx>>1)&3)) covers all 8 quads twice over 16 tx = 2-phase
// floor. (Round 6's consecutive codes + (row>>3)&3 swizzle collapsed to 4
// quads -> 4-way -> 2.36e8 conflict cycles.) A reads: 4 distinct addrs on 4
// quads, 16-way broadcast: conflict-free.
// Registers: ~124 VGPR (4 waves/SIMD), short prefetch; WRITE_SIZE ~2e3 is
// the no-spill tripwire (rounds 1-2: allocator squeeze -> GBs of scratch).
__global__ void __launch_bounds__(256)
vq_argmin_k(const float* __restrict__ z, const float* __restrict__ emb,
            const float* __restrict__ An, const float* __restrict__ Ce,
            float* __restrict__ cand_d, int* __restrict__ cand_i) {
  __shared__ float As[128 * 16];   // [row][16 c], k-group XOR-swizzled by (row>>3)&3
  __shared__ float Bs[128 * 16];   // [code][16 c], k-group XOR-swizzled by (code>>1)&3
  __shared__ float redd[128 * 16];
  __shared__ int   redi[128 * 16];

  const int t  = threadIdx.x;
  const int tx = t & 15;           // code group (8 codes, stride 16)
  const int ty = t >> 4;           // row group (8 consecutive rows)
  const int tile  = blockIdx.x >> 3;
  const int slice = blockIdx.x & 7;
  const int rbase = tile * 128;    // never crosses the 1024-hw batch edge
  const int k0    = slice * 1024;

  const float* zb = z + ((size_t)(rbase >> 10)) * BSTRIDE + (rbase & 1023);

  float best[8];
  int   bidx[8];
#pragma unroll
  for (int ri = 0; ri < 8; ++ri) { best[ri] = 3.4028235e38f; bidx[ri] = 0; }

  float acc[8][8];
#pragma unroll
  for (int ri = 0; ri < 8; ++ri)
#pragma unroll
    for (int ci = 0; ci < 8; ++ci) acc[ri][ci] = 0.f;

  // staging thread mappings
  const int a_c    = t >> 4;        // c_local 0..15 (one c, 8 hw)
  const int a_hw   = (t & 15) * 8;  // 8 consecutive rows
  const int b_code = t >> 1;        // code 0..127
  const int b_g0   = (t & 1) * 2;   // k-groups {0,1} or {2,3}
  const int b_sw   = (t >> 2) & 3;  // (b_code>>1)&3

  // swizzle constants
  const int a_sw_col = (a_c & 3);           // in-group float offset for A store
  const int a_grp    = (a_c >> 2);          // k-group of staged c
  const int rd_a_sw  = ty & 3;              // A read swizzle ((row>>3)&3)
  const int rd_b_sw  = (tx >> 1) & 3;       // B read swizzle ((code>>1)&3, code=tx+16ci)

  for (int kc = 0; kc < 8; ++kc) {
    const int kbase = k0 + kc * 128;
#pragma unroll 1
    for (int cc = 0; cc < 16; ++cc) {
      // short prefetch: issue just before barrier; regs die at the stores
      const float* zsrc = zb + (size_t)(cc * 16 + a_c) * HWS + a_hw;
      const float4 pa0 = *(const float4*)(zsrc);
      const float4 pa1 = *(const float4*)(zsrc + 4);
      const float* bsrc = emb + (size_t)(kbase + b_code) * CDIM + cc * 16 + b_g0 * 4;
      const float4 pb0 = *(const float4*)(bsrc);
      const float4 pb1 = *(const float4*)(bsrc + 4);

      __syncthreads();                      // prior compute done with As/Bs
      {
        // A transpose-store: 8 scalar stores, k-group swizzled per row
        const float va[8] = {pa0.x, pa0.y, pa0.z, pa0.w, pa1.x, pa1.y, pa1.z, pa1.w};
#pragma unroll
        for (int j = 0; j < 8; ++j) {
          const int row = a_hw + j;
          const int col = ((a_grp ^ ((row >> 3) & 3)) << 2) | a_sw_col;
          As[(row << 4) + col] = va[j];
        }
        // B store: two aligned float4 at swizzled k-group slots
        *(float4*)&Bs[(b_code << 4) + (((b_g0 + 0) ^ b_sw) << 2)] = pb0;
        *(float4*)&Bs[(b_code << 4) + (((b_g0 + 1) ^ b_sw) << 2)] = pb1;
      }
      __syncthreads();                      // staged data visible

      // 8x8 micro-tile over 16 k: 1024 FMA instrs, 64 b128 reads
#pragma unroll
      for (int g = 0; g < 4; ++g) {
        float4 bf[8];
#pragma unroll
        for (int ci = 0; ci < 8; ++ci)
          bf[ci] = *(const float4*)&Bs[((tx + ci * 16) << 4) + ((g ^ rd_b_sw) << 2)];
#pragma unroll
        for (int ri = 0; ri < 8; ++ri) {
          const float4 a = *(const float4*)&As[((ty * 8 + ri) << 4) + ((g ^ rd_a_sw) << 2)];
#pragma unroll
          for (int ci = 0; ci < 8; ++ci) {
            // chain order identical to rounds 1-6: bit-exact dots
            acc[ri][ci] = fmaf(a.x, bf[ci].x, fmaf(a.y, bf[ci].y,
                          fmaf(a.z, bf[ci].z, fmaf(a.w, bf[ci].w, acc[ri][ci]))));
          }
        }
      }
    }

    // fold per kc: dist = (A - 2*dot) + C with np's elementwise fp32 rounding.
    // thread's codes ascend with ci (tx + ci*16) + strict < -> lowest-index
    // min within thread; cross-thread/slice merges compare indices explicitly.
    {
      const int kkb = kbase + tx;
      float cearr[8];
#pragma unroll
      for (int ci = 0; ci < 8; ++ci) cearr[ci] = Ce[kkb + ci * 16];
#pragma unroll
      for (int ri = 0; ri < 8; ++ri) {
        const float Ar = An[rbase + ty * 8 + ri];   // reload (saves live regs)
#pragma unroll
        for (int ci = 0; ci < 8; ++ci) {
          const float d = (Ar - 2.0f * acc[ri][ci]) + cearr[ci];
          if (d < best[ri]) { best[ri] = d; bidx[ri] = kkb + ci * 16; }
          acc[ri][ci] = 0.f;
        }
      }
    }
  }

  // cross-thread argmin per row (tie -> lower absolute index)
#pragma unroll
  for (int ri = 0; ri < 8; ++ri) {
    redd[(ty * 8 + ri) * 16 + tx] = best[ri];
    redi[(ty * 8 + ri) * 16 + tx] = bidx[ri];
  }
  __syncthreads();
  if (t < 128) {
    float bd = redd[t * 16];
    int   bi = redi[t * 16];
    for (int j = 1; j < 16; ++j) {
      const float d  = redd[t * 16 + j];
      const int   i2 = redi[t * 16 + j];
      if (d < bd || (d == bd && i2 < bi)) { bd = d; bi = i2; }
    }
    const int n = rbase + t;
    cand_d[n * 8 + slice] = bd;
    cand_i[n * 8 + slice] = bi;
  }
}

// -------- merge the 8 code-slices (tie -> lower index) --------
__global__ void vq_merge_k(const float* __restrict__ cand_d, const int* __restrict__ cand_i,
                           int* __restrict__ idx_final, float* __restrict__ idxf_out) {
  const int n = blockIdx.x * 256 + threadIdx.x;   // 16384
  float bd = cand_d[n * 8];
  int   bi = cand_i[n * 8];
#pragma unroll
  for (int s = 1; s < 8; ++s) {
    const float d  = cand_d[n * 8 + s];
    const int   i2 = cand_i[n * 8 + s];
    if (d < bd || (d == bd && i2 < bi)) { bd = d; bi = i2; }
  }
  idx_final[n] = bi;
  idxf_out[n] = (float)bi;
}

// -------- gather quantized, write straight-through output, accumulate loss ----
// quantized_st = z + (q - z) in fp32 (matches np rounding; != q exactly).
__launch_bounds__(256)
__global__ void vq_gather_loss_k(const float* __restrict__ z, const float* __restrict__ emb,
                                 const int* __restrict__ idx_final,
                                 float* __restrict__ qout, float* __restrict__ loss_acc) {
  __shared__ float Qs[32 * 260];
  __shared__ int   kidx[32];
  __shared__ float warp_s[4];
  const int t = threadIdx.x;
  const int rbase = blockIdx.x * 32;
  if (t < 32) kidx[t] = idx_final[rbase + t];
  __syncthreads();
  {
    const int r = t >> 3, cp = t & 7;
    const float4* er = (const float4*)(emb + (size_t)kidx[r] * CDIM);
#pragma unroll
    for (int j = 0; j < 8; ++j) {
      const int c4 = cp + j * 8;
      const float4 v = er[c4];
      *(float4*)&Qs[r * 260 + c4 * 4] = v;
    }
  }
  __syncthreads();
  const int b = rbase >> 10, hw0 = rbase & 1023;
  const float* zb = z + (size_t)b * BSTRIDE + hw0;
  float* qb = qout + (size_t)b * BSTRIDE + hw0;
  float s = 0.f;
  const int hwl = t & 31, cg = t >> 5;
  for (int i = 0; i < 32; ++i) {
    const int c = cg * 32 + i;
    const float q  = Qs[hwl * 260 + c];
    const size_t off = (size_t)c * HWS + hwl;
    const float zv = zb[off];
    const float d  = q - zv;
    qb[off] = zv + d;          // straight-through value, np rounding
    s += d * d;
  }
  for (int off = 32; off; off >>= 1) s += __shfl_down(s, off, 64);
  if ((t & 63) == 0) warp_s[t >> 6] = s;
  __syncthreads();
  if (t == 0) atomicAdd(loss_acc, warp_s[0] + warp_s[1] + warp_s[2] + warp_s[3]);
}

__global__ void vq_finalize_k(const float* __restrict__ loss_acc, float* __restrict__ out_loss) {
  const float m = loss_acc[0] * (1.0f / 4194304.0f);
  out_loss[0] = m;          // codebook_loss
  out_loss[1] = 0.25f * m;  // commitment_loss (BETA * same mean)
}

extern "C" void kernel_launch(void* const* d_in, const int* in_sizes, int n_in,
                              void* d_out, int out_size, void* d_ws, size_t ws_size,
                              hipStream_t stream) {
  (void)in_sizes; (void)n_in; (void)out_size; (void)ws_size;
  const float* z   = (const float*)d_in[0];
  const float* emb = (const float*)d_in[1];
  float* out      = (float*)d_out;
  float* q_out    = out;                 // [16,256,32,32]
  float* loss_out = out + 4194304;       // 2 scalars
  float* idxf_out = out + 4194306;       // [16,32,32] as float

  float* ws       = (float*)d_ws;
  float* An       = ws + WS_AN;
  float* Ce       = ws + WS_CE;
  float* cand_d   = ws + WS_CD;
  int*   cand_i   = (int*)(ws + WS_CI);
  int*   idx_fin  = (int*)(ws + WS_IDX);
  float* loss_acc = ws + WS_LOSS;

  hipMemsetAsync(loss_acc, 0, sizeof(float), stream);
  rownorm_z_k<<<64, 256, 0, stream>>>(z, An);
  rownorm_e_k<<<32, 256, 0, stream>>>(emb, Ce);
  vq_argmin_k<<<1024, 256, 0, stream>>>(z, emb, An, Ce, cand_d, cand_i);
  vq_merge_k<<<64, 256, 0, stream>>>(cand_d, cand_i, idx_fin, idxf_out);
  vq_gather_loss_k<<<512, 256, 0, stream>>>(z, emb, idx_fin, q_out, loss_acc);
  vq_finalize_k<<<1, 1, 0, stream>>>(loss_acc, loss_out);
}

// Round 8
// 938.998 us; speedup vs baseline: 1.1940x; 1.0664x over previous
//
#include <hip/hip_runtime.h>

// Problem constants
#define NROWS   16384      // 16*32*32 flattened (b,h,w) rows
#define KCODES  8192
#define CDIM    256
#define HWS     1024       // 32*32
#define BSTRIDE 262144     // 256*1024 floats per batch in z / out

// Workspace layout (float-unit offsets) -- 8 slices
#define WS_AN   0                         // ||x||^2 per row       [16384]
#define WS_CE   16384                     // ||e||^2 per code      [8192]
#define WS_CD   24576                     // cand dist [n*8+slice] [131072]
#define WS_CI   155648                    // cand idx  (int)       [131072]
#define WS_IDX  286720                    // final idx (int)       [16384]
#define WS_LOSS 303104                    // loss accumulator      [1]

// -------- row norms, replicating numpy pairwise_sum order exactly --------
__global__ void rownorm_z_k(const float* __restrict__ z, float* __restrict__ An) {
#pragma clang fp contract(off)
  int n = blockIdx.x * 256 + threadIdx.x;                    // 16384 threads
  const float* base = z + ((size_t)(n >> 10)) * BSTRIDE + (n & 1023);
  float hs[2];
  for (int h = 0; h < 2; ++h) {
    float r[8];
#pragma unroll
    for (int j = 0; j < 8; ++j) { float v = base[(size_t)(h * 128 + j) * HWS]; r[j] = v * v; }
    for (int m = 1; m < 16; ++m) {
#pragma unroll
      for (int j = 0; j < 8; ++j) { float v = base[(size_t)(h * 128 + m * 8 + j) * HWS]; r[j] += v * v; }
    }
    hs[h] = ((r[0] + r[1]) + (r[2] + r[3])) + ((r[4] + r[5]) + (r[6] + r[7]));
  }
  An[n] = hs[0] + hs[1];
}

__global__ void rownorm_e_k(const float* __restrict__ emb, float* __restrict__ Ce) {
#pragma clang fp contract(off)
  int n = blockIdx.x * 256 + threadIdx.x;                    // 8192 threads
  const float* base = emb + (size_t)n * CDIM;
  float hs[2];
  for (int h = 0; h < 2; ++h) {
    float r[8];
#pragma unroll
    for (int j = 0; j < 8; ++j) { float v = base[h * 128 + j]; r[j] = v * v; }
    for (int m = 1; m < 16; ++m) {
#pragma unroll
      for (int j = 0; j < 8; ++j) { float v = base[h * 128 + m * 8 + j]; r[j] += v * v; }
    }
    hs[h] = ((r[0] + r[1]) + (r[2] + r[3])) + ((r[4] + r[5]) + (r[6] + r[7]));
  }
  Ce[n] = hs[0] + hs[1];
}

// -------- fused distance + argmin --------
// 1024 blocks = 128 row-tiles (128 rows) x 8 code-slices (1024 codes each).
// 256 threads = 16 tx x 16 ty. Micro-tile 8 rows x 8 codes. 32-c superchunks.
//
// LDS geometry (round-7 lesson): a 64B row confines accesses to 4 bank-quads
// no matter the swizzle; 128B rows (32 floats) + 3-bit XOR swizzle
// col=((kg^swz)<<2)|wi spread over all 8 quads:
//   A reads:  quad = g ^ (ty&7), 4 distinct/wave -> 1 phase (conflict-free)
//   B reads:  quad = g ^ (tx&7), 8 quads x 2     -> 2 phases (free, m136)
//   A stores: bank = 4*((t&15)&7) + (t>>4), all 32 banks 2-way (free)
//   B stores: 64 distinct b128 addrs, 8/quad     -> 8-phase floor
// Superchunk = 32 c -> barrier count halves (64 iters). Reduction arrays
// alias As/Bs (LDS stays 32KB -> 4+ blocks/CU).
// Registers: acc 64 + bf 32 + a 4 + best/bidx 16 + addr ~12 ~= 128 (4 w/SIMD);
// WRITE_SIZE ~8e3 is the no-spill tripwire (rounds 1-2).
__global__ void __launch_bounds__(256)
vq_argmin_k(const float* __restrict__ z, const float* __restrict__ emb,
            const float* __restrict__ An, const float* __restrict__ Ce,
            float* __restrict__ cand_d, int* __restrict__ cand_i) {
  __shared__ float smem[8192];     // 32 KB: As=[0,4096), Bs=[4096,8192)
  float* As = smem;                // [row][32 c], col XOR-swizzled by (row>>3)&7
  float* Bs = smem + 4096;         // [code][32 c], col XOR-swizzled by code&7

  const int t  = threadIdx.x;
  const int tx = t & 15;           // code group (8 codes, stride 16)
  const int ty = t >> 4;           // row group (8 consecutive rows)
  const int tile  = blockIdx.x >> 3;
  const int slice = blockIdx.x & 7;
  const int rbase = tile * 128;    // never crosses the 1024-hw batch edge
  const int k0    = slice * 1024;

  const float* zb = z + ((size_t)(rbase >> 10)) * BSTRIDE + (rbase & 1023);

  float best[8];
  int   bidx[8];
#pragma unroll
  for (int ri = 0; ri < 8; ++ri) { best[ri] = 3.4028235e38f; bidx[ri] = 0; }

  float acc[8][8];
#pragma unroll
  for (int ri = 0; ri < 8; ++ri)
#pragma unroll
    for (int ci = 0; ci < 8; ++ci) acc[ri][ci] = 0.f;

  // staging thread mappings
  const int a_c   = t >> 4;         // stages c_locals {a_c, a_c+16}, 8 rows each
  const int a_hw  = (t & 15) * 8;   // 8 consecutive rows
  const int a_swr = (t & 15) & 7;   // (row>>3)&7 for all 8 staged rows
  const int a_wi  = a_c & 3;
  const int a_kg1 = a_c >> 2;       // k-group of c1 (c2 = +4)
  const int acol1 = ((a_kg1 ^ a_swr) << 2) | a_wi;        // const per thread
  const int acol2 = (((a_kg1 + 4) ^ a_swr) << 2) | a_wi;
  const int b_code  = t >> 1;       // code 0..127
  const int b_cb    = (t & 1) * 16; // c_local base 0 or 16
  const int b_swr   = (t >> 1) & 7; // code&7
  const int b_kg0   = b_cb >> 2;    // 0 or 4

  const int rd_a_sw = ty & 7;
  const int rd_b_sw = tx & 7;

  for (int kc = 0; kc < 8; ++kc) {
    const int kbase = k0 + kc * 128;
#pragma unroll 1
    for (int sc = 0; sc < 8; ++sc) {
      // short prefetch: issue just before barrier; regs die at the stores
      const float* zsrc = zb + (size_t)(sc * 32 + a_c) * HWS + a_hw;
      const float4 pa0 = *(const float4*)(zsrc);
      const float4 pa1 = *(const float4*)(zsrc + 4);
      const float4 pa2 = *(const float4*)(zsrc + 16 * HWS);
      const float4 pa3 = *(const float4*)(zsrc + 16 * HWS + 4);
      const float* bsrc = emb + (size_t)(kbase + b_code) * CDIM + sc * 32 + b_cb;
      const float4 pb0 = *(const float4*)(bsrc);
      const float4 pb1 = *(const float4*)(bsrc + 4);
      const float4 pb2 = *(const float4*)(bsrc + 8);
      const float4 pb3 = *(const float4*)(bsrc + 12);

      __syncthreads();                      // prior compute done with As/Bs
      {
        // A transpose-store: 16 scalar stores, col const per thread (2-way free)
        const float va0[8] = {pa0.x, pa0.y, pa0.z, pa0.w, pa1.x, pa1.y, pa1.z, pa1.w};
        const float va1[8] = {pa2.x, pa2.y, pa2.z, pa2.w, pa3.x, pa3.y, pa3.z, pa3.w};
#pragma unroll
        for (int j = 0; j < 8; ++j) {
          const int rb = (a_hw + j) << 5;
          As[rb + acol1] = va0[j];
          As[rb + acol2] = va1[j];
        }
        // B store: four aligned float4 at swizzled k-group slots (8-phase floor)
        const int bb = b_code << 5;
        *(float4*)&Bs[bb + (((b_kg0 + 0) ^ b_swr) << 2)] = pb0;
        *(float4*)&Bs[bb + (((b_kg0 + 1) ^ b_swr) << 2)] = pb1;
        *(float4*)&Bs[bb + (((b_kg0 + 2) ^ b_swr) << 2)] = pb2;
        *(float4*)&Bs[bb + (((b_kg0 + 3) ^ b_swr) << 2)] = pb3;
      }
      __syncthreads();                      // staged data visible

      // 8x8 micro-tile over 32 k: 2048 FMA instrs, 128 b128 reads
#pragma unroll
      for (int g = 0; g < 8; ++g) {
        float4 bf[8];
#pragma unroll
        for (int ci = 0; ci < 8; ++ci)
          bf[ci] = *(const float4*)&Bs[((tx + ci * 16) << 5) + ((g ^ rd_b_sw) << 2)];
#pragma unroll
        for (int ri = 0; ri < 8; ++ri) {
          const float4 a = *(const float4*)&As[((ty * 8 + ri) << 5) + ((g ^ rd_a_sw) << 2)];
#pragma unroll
          for (int ci = 0; ci < 8; ++ci) {
            // 4-k groups ascending, k3-first nesting: identical to rounds 1-7
            acc[ri][ci] = fmaf(a.x, bf[ci].x, fmaf(a.y, bf[ci].y,
                          fmaf(a.z, bf[ci].z, fmaf(a.w, bf[ci].w, acc[ri][ci]))));
          }
        }
      }
    }

    // fold per kc: dist = (A - 2*dot) + C with np's elementwise fp32 rounding.
    // thread's codes ascend with ci (tx + ci*16) + strict < -> lowest-index
    // min within thread; cross-thread/slice merges compare indices explicitly.
    {
      const int kkb = kbase + tx;
      float cearr[8];
#pragma unroll
      for (int ci = 0; ci < 8; ++ci) cearr[ci] = Ce[kkb + ci * 16];
#pragma unroll
      for (int ri = 0; ri < 8; ++ri) {
        const float Ar = An[rbase + ty * 8 + ri];   // reload (saves live regs)
#pragma unroll
        for (int ci = 0; ci < 8; ++ci) {
          const float d = (Ar - 2.0f * acc[ri][ci]) + cearr[ci];
          if (d < best[ri]) { best[ri] = d; bidx[ri] = kkb + ci * 16; }
          acc[ri][ci] = 0.f;
        }
      }
    }
  }

  // cross-thread argmin per row (tie -> lower absolute index); alias smem
  __syncthreads();                 // compute done; safe to overwrite As/Bs
  float* redd = smem;              // [128][16]
  int*   redi = (int*)(smem + 2048);
#pragma unroll
  for (int ri = 0; ri < 8; ++ri) {
    redd[(ty * 8 + ri) * 16 + tx] = best[ri];
    redi[(ty * 8 + ri) * 16 + tx] = bidx[ri];
  }
  __syncthreads();
  if (t < 128) {
    float bd = redd[t * 16];
    int   bi = redi[t * 16];
    for (int j = 1; j < 16; ++j) {
      const float d  = redd[t * 16 + j];
      const int   i2 = redi[t * 16 + j];
      if (d < bd || (d == bd && i2 < bi)) { bd = d; bi = i2; }
    }
    const int n = rbase + t;
    cand_d[n * 8 + slice] = bd;
    cand_i[n * 8 + slice] = bi;
  }
}

// -------- merge the 8 code-slices (tie -> lower index) --------
__global__ void vq_merge_k(const float* __restrict__ cand_d, const int* __restrict__ cand_i,
                           int* __restrict__ idx_final, float* __restrict__ idxf_out) {
  const int n = blockIdx.x * 256 + threadIdx.x;   // 16384
  float bd = cand_d[n * 8];
  int   bi = cand_i[n * 8];
#pragma unroll
  for (int s = 1; s < 8; ++s) {
    const float d  = cand_d[n * 8 + s];
    const int   i2 = cand_i[n * 8 + s];
    if (d < bd || (d == bd && i2 < bi)) { bd = d; bi = i2; }
  }
  idx_final[n] = bi;
  idxf_out[n] = (float)bi;
}

// -------- gather quantized, write straight-through output, accumulate loss ----
// quantized_st = z + (q - z) in fp32 (matches np rounding; != q exactly).
__launch_bounds__(256)
__global__ void vq_gather_loss_k(const float* __restrict__ z, const float* __restrict__ emb,
                                 const int* __restrict__ idx_final,
                                 float* __restrict__ qout, float* __restrict__ loss_acc) {
  __shared__ float Qs[32 * 260];
  __shared__ int   kidx[32];
  __shared__ float warp_s[4];
  const int t = threadIdx.x;
  const int rbase = blockIdx.x * 32;
  if (t < 32) kidx[t] = idx_final[rbase + t];
  __syncthreads();
  {
    const int r = t >> 3, cp = t & 7;
    const float4* er = (const float4*)(emb + (size_t)kidx[r] * CDIM);
#pragma unroll
    for (int j = 0; j < 8; ++j) {
      const int c4 = cp + j * 8;
      const float4 v = er[c4];
      *(float4*)&Qs[r * 260 + c4 * 4] = v;
    }
  }
  __syncthreads();
  const int b = rbase >> 10, hw0 = rbase & 1023;
  const float* zb = z + (size_t)b * BSTRIDE + hw0;
  float* qb = qout + (size_t)b * BSTRIDE + hw0;
  float s = 0.f;
  const int hwl = t & 31, cg = t >> 5;
  for (int i = 0; i < 32; ++i) {
    const int c = cg * 32 + i;
    const float q  = Qs[hwl * 260 + c];
    const size_t off = (size_t)c * HWS + hwl;
    const float zv = zb[off];
    const float d  = q - zv;
    qb[off] = zv + d;          // straight-through value, np rounding
    s += d * d;
  }
  for (int off = 32; off; off >>= 1) s += __shfl_down(s, off, 64);
  if ((t & 63) == 0) warp_s[t >> 6] = s;
  __syncthreads();
  if (t == 0) atomicAdd(loss_acc, warp_s[0] + warp_s[1] + warp_s[2] + warp_s[3]);
}

__global__ void vq_finalize_k(const float* __restrict__ loss_acc, float* __restrict__ out_loss) {
  const float m = loss_acc[0] * (1.0f / 4194304.0f);
  out_loss[0] = m;          // codebook_loss
  out_loss[1] = 0.25f * m;  // commitment_loss (BETA * same mean)
}

extern "C" void kernel_launch(void* const* d_in, const int* in_sizes, int n_in,
                              void* d_out, int out_size, void* d_ws, size_t ws_size,
                              hipStream_t stream) {
  (void)in_sizes; (void)n_in; (void)out_size; (void)ws_size;
  const float* z   = (const float*)d_in[0];
  const float* emb = (const float*)d_in[1];
  float* out      = (float*)d_out;
  float* q_out    = out;                 // [16,256,32,32]
  float* loss_out = out + 4194304;       // 2 scalars
  float* idxf_out = out + 4194306;       // [16,32,32] as float

  float* ws       = (float*)d_ws;
  float* An       = ws + WS_AN;
  float* Ce       = ws + WS_CE;
  float* cand_d   = ws + WS_CD;
  int*   cand_i   = (int*)(ws + WS_CI);
  int*   idx_fin  = (int*)(ws + WS_IDX);
  float* loss_acc = ws + WS_LOSS;

  hipMemsetAsync(loss_acc, 0, sizeof(float), stream);
  rownorm_z_k<<<64, 256, 0, stream>>>(z, An);
  rownorm_e_k<<<32, 256, 0, stream>>>(emb, Ce);
  vq_argmin_k<<<1024, 256, 0, stream>>>(z, emb, An, Ce, cand_d, cand_i);
  vq_merge_k<<<64, 256, 0, stream>>>(cand_d, cand_i, idx_fin, idxf_out);
  vq_gather_loss_k<<<512, 256, 0, stream>>>(z, emb, idx_fin, q_out, loss_acc);
  vq_finalize_k<<<1, 1, 0, stream>>>(loss_acc, loss_out);
}